// Round 1
// baseline (1260.498 us; speedup 1.0000x reference)
//
#include <hip/hip_runtime.h>

#define H 2048
#define E 16
#define F 1408
#define FS 4096
#define T 2048
#define TOPK 4
#define CAP 2048
#define LDA 40  // old-path padded LDS row stride
#define NPADROWS (T * TOPK + E * 128)  // 10240 padded expert slots

typedef __bf16 bf16;
typedef bf16 bf16x4 __attribute__((ext_vector_type(4)));
typedef bf16 bf16x8 __attribute__((ext_vector_type(8)));
typedef float floatx4 __attribute__((ext_vector_type(4)));

static __device__ __forceinline__ floatx4 mfma16(bf16x8 a, bf16x8 b, floatx4 c) {
    return __builtin_amdgcn_mfma_f32_16x16x32_bf16(a, b, c, 0, 0, 0);
}

// async global->LDS, 16B per lane; LDS dest is wave-uniform base + lane*16
static __device__ __forceinline__ void gload16(const bf16* g, bf16* l) {
    __builtin_amdgcn_global_load_lds(
        (const __attribute__((address_space(1))) void*)g,
        (__attribute__((address_space(3))) void*)l, 16, 0, 0);
}

// ---------------- router: fp32 logits, softmax, top-4, scatter ----------------
__global__ __launch_bounds__(256) void router_kernel(
    const float* __restrict__ x, const float* __restrict__ wr,
    int* __restrict__ cnt, int* __restrict__ tokid, float* __restrict__ tokw) {
    const int wave = threadIdx.x >> 6;
    const int lane = threadIdx.x & 63;
    const int t = blockIdx.x * 4 + wave;
    if (t >= T) return;
    const float* xrow = x + (size_t)t * H;
    float xr[H / 64];
#pragma unroll
    for (int i = 0; i < H / 64; i++) xr[i] = xrow[lane + i * 64];
    float logits[E];
    for (int e = 0; e < E; e++) {
        const float* wrow = wr + (size_t)e * H;
        float p = 0.f;
#pragma unroll
        for (int i = 0; i < H / 64; i++) p += xr[i] * wrow[lane + i * 64];
        for (int off = 32; off; off >>= 1) p += __shfl_xor(p, off, 64);
        logits[e] = p;
    }
    float mx = logits[0];
    for (int e = 1; e < E; e++) mx = fmaxf(mx, logits[e]);
    float pr[E];
    float sum = 0.f;
    for (int e = 0; e < E; e++) { pr[e] = __expf(logits[e] - mx); sum += pr[e]; }
    float inv = 1.f / sum;
    for (int e = 0; e < E; e++) pr[e] *= inv;
    int sel[TOPK]; float sw[TOPK]; float wsum = 0.f;
    for (int k = 0; k < TOPK; k++) {
        float best = -1.f; int bi = 0;
        for (int e = 0; e < E; e++) if (pr[e] > best) { best = pr[e]; bi = e; }
        sel[k] = bi; sw[k] = best; wsum += best; pr[bi] = -2.f;
    }
    if (lane == 0) {
        float invw = 1.f / wsum;
        for (int k = 0; k < TOPK; k++) {
            int e = sel[k];
            int pos = atomicAdd(&cnt[e], 1);
            tokid[e * CAP + pos] = t;
            tokw[e * CAP + pos] = sw[k] * invw;
        }
    }
}

// pad!=0: prefix entries rounded up to 128 rows per expert
__global__ void prefix_kernel(const int* __restrict__ cnt, int* __restrict__ prefix, int pad) {
    if (threadIdx.x == 0) {
        int s = 0;
        for (int e = 0; e < E; e++) {
            prefix[e] = s;
            int c = cnt[e];
            s += pad ? ((c + 127) & ~127) : c;
        }
        prefix[E] = s;
    }
}

// ---------------- pre-pass: x -> bf16 (swizzled) ----------------
__global__ __launch_bounds__(256) void convert_x(const float* __restrict__ x,
                                                 bf16* __restrict__ Xb) {
    const int t = threadIdx.x;
    const int row = blockIdx.x * 8 + (t >> 5);
    const int l32 = t & 31;
    const float* src = x + (size_t)row * H;
    bf16* dst = Xb + (size_t)row * H;
    const int xk = (row & 3) << 3;
#pragma unroll
    for (int i = 0; i < 8; i++) {
        int kb = l32 * 8 + i * 256;
        float4 a = *(const float4*)(src + kb);
        float4 b = *(const float4*)(src + kb + 4);
        bf16x8 v;
        v[0] = (bf16)a.x; v[1] = (bf16)a.y; v[2] = (bf16)a.z; v[3] = (bf16)a.w;
        v[4] = (bf16)b.x; v[5] = (bf16)b.y; v[6] = (bf16)b.z; v[7] = (bf16)b.w;
        *(bf16x8*)(dst + (kb ^ xk)) = v;
    }
}

// ---------------- pre-pass: gathered+scaled expert tokens (swizzled) ----------------
__global__ __launch_bounds__(256) void gather_x(
    const float* __restrict__ x, const int* __restrict__ cnt,
    const int* __restrict__ prefixPad, const int* __restrict__ tokid,
    const float* __restrict__ tokw, bf16* __restrict__ Xg) {
    const int e = blockIdx.y;
    const int s0 = blockIdx.x * 8;
    const int n = cnt[e];
    if (s0 >= n) return;
    const int t = threadIdx.x;
    const int sl = s0 + (t >> 5);
    const int l32 = t & 31;
    if (sl >= n) return;
    const int tok = tokid[e * CAP + sl];
    const float w = tokw[e * CAP + sl];
    const int row = prefixPad[e] + sl;
    const float* src = x + (size_t)tok * H;
    bf16* dst = Xg + (size_t)row * H;
    const int xk = (row & 3) << 3;
#pragma unroll
    for (int i = 0; i < 8; i++) {
        int kb = l32 * 8 + i * 256;
        float4 a = *(const float4*)(src + kb);
        float4 b = *(const float4*)(src + kb + 4);
        bf16x8 v;
        v[0] = (bf16)(a.x * w); v[1] = (bf16)(a.y * w);
        v[2] = (bf16)(a.z * w); v[3] = (bf16)(a.w * w);
        v[4] = (bf16)(b.x * w); v[5] = (bf16)(b.y * w);
        v[6] = (bf16)(b.z * w); v[7] = (bf16)(b.w * w);
        *(bf16x8*)(dst + (kb ^ xk)) = v;
    }
}

// ---------------- pre-pass: transpose fp32 [z][R][C] -> bf16 [z][C][R], swizzled ----------------
__global__ __launch_bounds__(256) void transpose_cvt(
    const float* __restrict__ src, bf16* __restrict__ dst, int R, int C) {
    __shared__ bf16 tile[32][36];
    const int t = threadIdx.x;
    const size_t zb = (size_t)blockIdx.z * R * C;
    const int r0 = blockIdx.y * 32, c0 = blockIdx.x * 32;
    {
        const int rl = t >> 3, c4 = (t & 7) * 4;
        float4 v = *(const float4*)(src + zb + (size_t)(r0 + rl) * C + c0 + c4);
        tile[rl][c4 + 0] = (bf16)v.x;
        tile[rl][c4 + 1] = (bf16)v.y;
        tile[rl][c4 + 2] = (bf16)v.z;
        tile[rl][c4 + 3] = (bf16)v.w;
    }
    __syncthreads();
    {
        const int cl = t >> 3, r4 = (t & 7) * 4;
        bf16x4 o;
        o[0] = tile[r4 + 0][cl];
        o[1] = tile[r4 + 1][cl];
        o[2] = tile[r4 + 2][cl];
        o[3] = tile[r4 + 3][cl];
        const int cg = c0 + cl;
        *(bf16x4*)(dst + zb + (size_t)cg * R + ((r0 + r4) ^ ((cg & 3) << 3))) = o;
    }
}

// ---------------- stage 1 (new): bf16 inputs, global_load_lds, swizzled LDS ----------------
// A: [rows][H] bf16 swizzled; BgT/BuT: [nF][H] bf16 swizzled; hout: [rows][nF] bf16 swizzled.
template <bool EXPERT>
__global__ __launch_bounds__(256, 2) void s1_gemm(
    const bf16* __restrict__ Abuf, const bf16* __restrict__ BgT,
    const bf16* __restrict__ BuT, bf16* __restrict__ hout,
    const int* __restrict__ cnt, const int* __restrict__ prefixPad, int nF) {
    __shared__ __align__(16) bf16 As[128 * 32];
    __shared__ __align__(16) bf16 Bgs[128 * 32];
    __shared__ __align__(16) bf16 Bus[128 * 32];
    const int tid = threadIdx.x;
    const int n0 = blockIdx.x * 128;
    const int m0 = blockIdx.y * 128;
    int ne = T;
    const bf16* A = Abuf;
    const bf16* bg = BgT;
    const bf16* bu = BuT;
    bf16* hb = hout;
    if (EXPERT) {
        const int e = blockIdx.z;
        ne = cnt[e];
        if (m0 >= ne) return;
        const int pp = prefixPad[e];
        A = Abuf + (size_t)pp * H;
        bg = BgT + (size_t)e * F * H;
        bu = BuT + (size_t)e * F * H;
        hb = hout + (size_t)pp * F;
    }
    const int lane = tid & 63;
    const int wave = tid >> 6;
    const int sr = wave * 32 + (lane >> 2);     // staging row (j=0); j=1 adds 16
    const int sc = (lane & 3) * 8;              // element col within 32-elem k window
    const int lo = wave * 1024;                  // wave-uniform LDS element base
    const bf16* aSrc = A + (size_t)(m0 + sr) * H + sc;
    const bf16* gSrc = bg + (size_t)(n0 + sr) * H + sc;
    const bf16* uSrc = bu + (size_t)(n0 + sr) * H + sc;

    const int m_ = lane & 15;
    const int quad = lane >> 4;
    const int wm = (wave & 1) * 64;
    const int wn = (wave >> 1) * 64;
    const int xq = (quad ^ (m_ & 3)) << 3;      // swizzled k-group offset (elements)

    floatx4 accg[4][4], accu[4][4];
#pragma unroll
    for (int i = 0; i < 4; i++)
#pragma unroll
        for (int j = 0; j < 4; j++) {
            accg[i][j] = (floatx4){0.f, 0.f, 0.f, 0.f};
            accu[i][j] = (floatx4){0.f, 0.f, 0.f, 0.f};
        }

    for (int k0 = 0; k0 < H; k0 += 32) {
        gload16(aSrc + k0, &As[lo]);
        gload16(aSrc + k0 + (size_t)16 * H, &As[lo + 512]);
        gload16(gSrc + k0, &Bgs[lo]);
        gload16(gSrc + k0 + (size_t)16 * H, &Bgs[lo + 512]);
        gload16(uSrc + k0, &Bus[lo]);
        gload16(uSrc + k0 + (size_t)16 * H, &Bus[lo + 512]);
        __syncthreads();
        bf16x8 af[4], bgf[4], buf_[4];
#pragma unroll
        for (int mi = 0; mi < 4; mi++)
            af[mi] = *(const bf16x8*)&As[(wm + mi * 16 + m_) * 32 + xq];
#pragma unroll
        for (int ni = 0; ni < 4; ni++) {
            bgf[ni] = *(const bf16x8*)&Bgs[(wn + ni * 16 + m_) * 32 + xq];
            buf_[ni] = *(const bf16x8*)&Bus[(wn + ni * 16 + m_) * 32 + xq];
        }
#pragma unroll
        for (int mi = 0; mi < 4; mi++)
#pragma unroll
            for (int ni = 0; ni < 4; ni++) {
                accg[mi][ni] = mfma16(af[mi], bgf[ni], accg[mi][ni]);
                accu[mi][ni] = mfma16(af[mi], buf_[ni], accu[mi][ni]);
            }
        __syncthreads();
    }

#pragma unroll
    for (int mi = 0; mi < 4; mi++)
#pragma unroll
        for (int ni = 0; ni < 4; ni++)
#pragma unroll
            for (int r = 0; r < 4; r++) {
                int row = m0 + wm + mi * 16 + quad * 4 + r;
                int col = n0 + wn + ni * 16 + m_;
                if (!EXPERT || row < ne) {
                    float g = accg[mi][ni][r];
                    float u = accu[mi][ni][r];
                    float hv = g / (1.f + __expf(-g)) * u;
                    hb[(size_t)row * nF + (col ^ ((row & 3) << 3))] = (bf16)hv;
                }
            }
}

// ---------------- stage 2 (new): out (+)= h @ WdT ----------------
// hin: [rows][nK] bf16 swizzled; BdT: [H][nK] bf16 swizzled.
template <bool EXPERT>
__global__ __launch_bounds__(256, 3) void s2_gemm(
    const bf16* __restrict__ hin, const bf16* __restrict__ BdT,
    float* __restrict__ out, const int* __restrict__ cnt,
    const int* __restrict__ prefixPad, const int* __restrict__ tokid,
    const float* __restrict__ tokw, int nK) {
    __shared__ __align__(16) bf16 As[128 * 32];
    __shared__ __align__(16) bf16 Bs[128 * 32];
    const int tid = threadIdx.x;
    const int n0 = blockIdx.x * 128;  // over H
    const int m0 = blockIdx.y * 128;  // over rows/slots
    int ne = T;
    const bf16* hb = hin;
    const bf16* bd = BdT;
    int e = 0;
    if (EXPERT) {
        e = blockIdx.z;
        ne = cnt[e];
        if (m0 >= ne) return;
        hb = hin + (size_t)prefixPad[e] * F;
        bd = BdT + (size_t)e * F * H;  // per-expert [H][F]
    }
    const int lane = tid & 63;
    const int wave = tid >> 6;
    const int sr = wave * 32 + (lane >> 2);
    const int sc = (lane & 3) * 8;
    const int lo = wave * 1024;
    const bf16* aSrc = hb + (size_t)(m0 + sr) * nK + sc;
    const bf16* bSrc = bd + (size_t)(n0 + sr) * nK + sc;

    const int m_ = lane & 15;
    const int quad = lane >> 4;
    const int wm = (wave & 1) * 64;
    const int wn = (wave >> 1) * 64;
    const int xq = (quad ^ (m_ & 3)) << 3;

    floatx4 acc[4][4];
#pragma unroll
    for (int i = 0; i < 4; i++)
#pragma unroll
        for (int j = 0; j < 4; j++) acc[i][j] = (floatx4){0.f, 0.f, 0.f, 0.f};

    for (int k0 = 0; k0 < nK; k0 += 32) {
        gload16(aSrc + k0, &As[lo]);
        gload16(aSrc + k0 + (size_t)16 * nK, &As[lo + 512]);
        gload16(bSrc + k0, &Bs[lo]);
        gload16(bSrc + k0 + (size_t)16 * nK, &Bs[lo + 512]);
        __syncthreads();
        bf16x8 af[4], bf_[4];
#pragma unroll
        for (int mi = 0; mi < 4; mi++)
            af[mi] = *(const bf16x8*)&As[(wm + mi * 16 + m_) * 32 + xq];
#pragma unroll
        for (int ni = 0; ni < 4; ni++)
            bf_[ni] = *(const bf16x8*)&Bs[(wn + ni * 16 + m_) * 32 + xq];
#pragma unroll
        for (int mi = 0; mi < 4; mi++)
#pragma unroll
            for (int ni = 0; ni < 4; ni++)
                acc[mi][ni] = mfma16(af[mi], bf_[ni], acc[mi][ni]);
        __syncthreads();
    }

#pragma unroll
    for (int mi = 0; mi < 4; mi++)
#pragma unroll
        for (int ni = 0; ni < 4; ni++)
#pragma unroll
            for (int r = 0; r < 4; r++) {
                int row = m0 + wm + mi * 16 + quad * 4 + r;
                int col = n0 + wn + ni * 16 + m_;
                if (EXPERT) {
                    if (row < ne) {
                        int t = tokid[e * CAP + row];
                        float wgt = tokw[e * CAP + row];
                        atomicAdd(out + (size_t)t * H + col, acc[mi][ni][r] * wgt);
                    }
                } else {
                    out[(size_t)row * H + col] = acc[mi][ni][r];
                }
            }
}

// ================= OLD PATH (fallback when workspace too small) =================
template <bool EXPERT>
__global__ __launch_bounds__(256) void stage1_gemm(
    const float* __restrict__ x, const float* __restrict__ wg_all,
    const float* __restrict__ wu_all, bf16* __restrict__ hout,
    const int* __restrict__ cnt, const int* __restrict__ prefix,
    const int* __restrict__ tokid, const float* __restrict__ tokw, int nF) {
    __shared__ __align__(16) bf16 As[128 * LDA];
    __shared__ __align__(16) bf16 Bg[128 * LDA];
    __shared__ __align__(16) bf16 Bu[128 * LDA];
    const int tid = threadIdx.x;
    const int n0 = blockIdx.x * 128;
    const int m0 = blockIdx.y * 128;
    int e = 0, ne = T;
    const float* wg = wg_all;
    const float* wu = wu_all;
    bf16* hb = hout;
    if (EXPERT) {
        e = blockIdx.z;
        ne = cnt[e];
        if (m0 >= ne) return;
        wg = wg_all + (size_t)e * H * F;
        wu = wu_all + (size_t)e * H * F;
        hb = hout + (size_t)prefix[e] * F;
    }
    const float* aptr[4]; float ascl[4]; bool avalid[4];
#pragma unroll
    for (int j = 0; j < 4; j++) {
        int idx = tid + j * 256;
        int r = idx >> 3;
        int kq = (idx & 7) * 4;
        int slot = m0 + r;
        if (EXPERT) {
            if (slot < ne) {
                int t = tokid[e * CAP + slot];
                aptr[j] = x + (size_t)t * H + kq;
                ascl[j] = tokw[e * CAP + slot];
                avalid[j] = true;
            } else { aptr[j] = x; ascl[j] = 0.f; avalid[j] = false; }
        } else {
            aptr[j] = x + (size_t)slot * H + kq;
            ascl[j] = 1.f; avalid[j] = true;
        }
    }
    const int lane = tid & 63;
    const int m = lane & 15;
    const int quad = lane >> 4;
    const int wave = tid >> 6;
    const int wm = (wave & 1) * 64;
    const int wn = (wave >> 1) * 64;
    floatx4 accg[4][4], accu[4][4];
#pragma unroll
    for (int i = 0; i < 4; i++)
#pragma unroll
        for (int j = 0; j < 4; j++) {
            accg[i][j] = (floatx4){0.f, 0.f, 0.f, 0.f};
            accu[i][j] = (floatx4){0.f, 0.f, 0.f, 0.f};
        }
    for (int k0 = 0; k0 < H; k0 += 32) {
#pragma unroll
        for (int j = 0; j < 4; j++) {
            int idx = tid + j * 256;
            int r = idx >> 3;
            int kq = (idx & 7) * 4;
            float4 v = make_float4(0.f, 0.f, 0.f, 0.f);
            if (!EXPERT || avalid[j]) v = *(const float4*)(aptr[j] + k0);
            bf16x4 bv;
            bv[0] = (bf16)(v.x * ascl[j]); bv[1] = (bf16)(v.y * ascl[j]);
            bv[2] = (bf16)(v.z * ascl[j]); bv[3] = (bf16)(v.w * ascl[j]);
            *(bf16x4*)&As[r * LDA + kq] = bv;
        }
#pragma unroll
        for (int j = 0; j < 4; j++) {
            int idx = tid + j * 256;
            int kk = idx >> 5;
            int n4 = (idx & 31) * 4;
            float4 vg = *(const float4*)(wg + (size_t)(k0 + kk) * nF + n0 + n4);
            Bg[(n4 + 0) * LDA + kk] = (bf16)vg.x;
            Bg[(n4 + 1) * LDA + kk] = (bf16)vg.y;
            Bg[(n4 + 2) * LDA + kk] = (bf16)vg.z;
            Bg[(n4 + 3) * LDA + kk] = (bf16)vg.w;
            float4 vu = *(const float4*)(wu + (size_t)(k0 + kk) * nF + n0 + n4);
            Bu[(n4 + 0) * LDA + kk] = (bf16)vu.x;
            Bu[(n4 + 1) * LDA + kk] = (bf16)vu.y;
            Bu[(n4 + 2) * LDA + kk] = (bf16)vu.z;
            Bu[(n4 + 3) * LDA + kk] = (bf16)vu.w;
        }
        __syncthreads();
        bf16x8 af[4], bgf[4], buf_[4];
#pragma unroll
        for (int mi = 0; mi < 4; mi++)
            af[mi] = *(const bf16x8*)&As[(wm + mi * 16 + m) * LDA + quad * 8];
#pragma unroll
        for (int ni = 0; ni < 4; ni++) {
            bgf[ni] = *(const bf16x8*)&Bg[(wn + ni * 16 + m) * LDA + quad * 8];
            buf_[ni] = *(const bf16x8*)&Bu[(wn + ni * 16 + m) * LDA + quad * 8];
        }
#pragma unroll
        for (int mi = 0; mi < 4; mi++)
#pragma unroll
            for (int ni = 0; ni < 4; ni++) {
                accg[mi][ni] = mfma16(af[mi], bgf[ni], accg[mi][ni]);
                accu[mi][ni] = mfma16(af[mi], buf_[ni], accu[mi][ni]);
            }
        __syncthreads();
    }
#pragma unroll
    for (int mi = 0; mi < 4; mi++)
#pragma unroll
        for (int ni = 0; ni < 4; ni++)
#pragma unroll
            for (int r = 0; r < 4; r++) {
                int row = m0 + wm + mi * 16 + quad * 4 + r;
                int col = n0 + wn + ni * 16 + m;
                if (!EXPERT || row < ne) {
                    float g = accg[mi][ni][r];
                    float u = accu[mi][ni][r];
                    float hv = g / (1.f + __expf(-g)) * u;
                    hb[(size_t)row * nF + col] = (bf16)hv;
                }
            }
}

template <bool EXPERT>
__global__ __launch_bounds__(256) void stage2_gemm(
    const bf16* __restrict__ hin, const float* __restrict__ wd_all,
    float* __restrict__ out, const int* __restrict__ cnt,
    const int* __restrict__ prefix, const int* __restrict__ tokid,
    const float* __restrict__ tokw, int nK) {
    __shared__ __align__(16) bf16 As[128 * LDA];
    __shared__ __align__(16) bf16 Bs[128 * LDA];
    const int tid = threadIdx.x;
    const int n0 = blockIdx.x * 128;
    const int m0 = blockIdx.y * 128;
    int e = 0, ne = T;
    const float* wd = wd_all;
    const bf16* hb = hin;
    if (EXPERT) {
        e = blockIdx.z;
        ne = cnt[e];
        if (m0 >= ne) return;
        wd = wd_all + (size_t)e * F * H;
        hb = hin + (size_t)prefix[e] * F;
    }
    const int lane = tid & 63;
    const int m = lane & 15;
    const int quad = lane >> 4;
    const int wave = tid >> 6;
    const int wm = (wave & 1) * 64;
    const int wn = (wave >> 1) * 64;
    floatx4 acc[4][4];
#pragma unroll
    for (int i = 0; i < 4; i++)
#pragma unroll
        for (int j = 0; j < 4; j++) acc[i][j] = (floatx4){0.f, 0.f, 0.f, 0.f};
    for (int k0 = 0; k0 < nK; k0 += 32) {
#pragma unroll
        for (int j = 0; j < 2; j++) {
            int idx = tid + j * 256;
            int r = idx >> 2;
            int k8 = (idx & 3) * 8;
            bf16x8 v;
#pragma unroll
            for (int q = 0; q < 8; q++) v[q] = (bf16)0.f;
            int row = m0 + r;
            if (!EXPERT || row < ne)
                v = *(const bf16x8*)(hb + (size_t)row * nK + k0 + k8);
            *(bf16x8*)&As[r * LDA + k8] = v;
        }
#pragma unroll
        for (int j = 0; j < 4; j++) {
            int idx = tid + j * 256;
            int kk = idx >> 5;
            int n4 = (idx & 31) * 4;
            float4 v = *(const float4*)(wd + (size_t)(k0 + kk) * H + n0 + n4);
            Bs[(n4 + 0) * LDA + kk] = (bf16)v.x;
            Bs[(n4 + 1) * LDA + kk] = (bf16)v.y;
            Bs[(n4 + 2) * LDA + kk] = (bf16)v.z;
            Bs[(n4 + 3) * LDA + kk] = (bf16)v.w;
        }
        __syncthreads();
        bf16x8 af[4], bf_[4];
#pragma unroll
        for (int mi = 0; mi < 4; mi++)
            af[mi] = *(const bf16x8*)&As[(wm + mi * 16 + m) * LDA + quad * 8];
#pragma unroll
        for (int ni = 0; ni < 4; ni++)
            bf_[ni] = *(const bf16x8*)&Bs[(wn + ni * 16 + m) * LDA + quad * 8];
#pragma unroll
        for (int mi = 0; mi < 4; mi++)
#pragma unroll
            for (int ni = 0; ni < 4; ni++)
                acc[mi][ni] = mfma16(af[mi], bf_[ni], acc[mi][ni]);
        __syncthreads();
    }
#pragma unroll
    for (int mi = 0; mi < 4; mi++)
#pragma unroll
        for (int ni = 0; ni < 4; ni++)
#pragma unroll
            for (int r = 0; r < 4; r++) {
                int row = m0 + wm + mi * 16 + quad * 4 + r;
                int col = n0 + wn + ni * 16 + m;
                if (EXPERT) {
                    if (row < ne) {
                        int t = tokid[e * CAP + row];
                        float wgt = tokw[e * CAP + row];
                        atomicAdd(out + (size_t)t * H + col, acc[mi][ni][r] * wgt);
                    }
                } else {
                    out[(size_t)row * H + col] = acc[mi][ni][r];
                }
            }
}

extern "C" void kernel_launch(void* const* d_in, const int* in_sizes, int n_in,
                              void* d_out, int out_size, void* d_ws, size_t ws_size,
                              hipStream_t stream) {
    const float* x = (const float*)d_in[0];
    const float* w_router = (const float*)d_in[1];
    const float* Wg = (const float*)d_in[2];
    const float* Wu = (const float*)d_in[3];
    const float* Wd = (const float*)d_in[4];
    const float* Wg_s = (const float*)d_in[5];
    const float* Wu_s = (const float*)d_in[6];
    const float* Wd_s = (const float*)d_in[7];
    float* out = (float*)d_out;

    char* w = (char*)d_ws;
    int* cnt = (int*)(w + 0);
    int* prefix = (int*)(w + 64);
    int* tokid = (int*)(w + 256);
    float* tokw = (float*)(w + 256 + (size_t)E * CAP * 4);

    // new-path workspace layout
    constexpr size_t OFF_XB = 262400;
    constexpr size_t OFF_XG = OFF_XB + (size_t)T * H * 2;
    constexpr size_t OFF_HS = OFF_XG + (size_t)NPADROWS * H * 2;
    constexpr size_t OFF_HB = OFF_HS + (size_t)T * FS * 2;
    constexpr size_t OFF_WGT = OFF_HB + (size_t)NPADROWS * F * 2;
    constexpr size_t OFF_WUT = OFF_WGT + (size_t)E * F * H * 2;
    constexpr size_t OFF_WDT = OFF_WUT + (size_t)E * F * H * 2;
    constexpr size_t OFF_WGS = OFF_WDT + (size_t)E * F * H * 2;
    constexpr size_t OFF_WUS = OFF_WGS + (size_t)H * FS * 2;
    constexpr size_t OFF_WDS = OFF_WUS + (size_t)H * FS * 2;
    constexpr size_t WS_NEED = OFF_WDS + (size_t)H * FS * 2;  // ~423.4 MB

    hipMemsetAsync(cnt, 0, 64, stream);
    router_kernel<<<T / 4, 256, 0, stream>>>(x, w_router, cnt, tokid, tokw);

    if (ws_size >= WS_NEED) {
        bf16* Xb = (bf16*)(w + OFF_XB);
        bf16* Xg = (bf16*)(w + OFF_XG);
        bf16* Hs = (bf16*)(w + OFF_HS);
        bf16* Hb = (bf16*)(w + OFF_HB);
        bf16* WgT = (bf16*)(w + OFF_WGT);
        bf16* WuT = (bf16*)(w + OFF_WUT);
        bf16* WdT = (bf16*)(w + OFF_WDT);
        bf16* WgsT = (bf16*)(w + OFF_WGS);
        bf16* WusT = (bf16*)(w + OFF_WUS);
        bf16* WdsT = (bf16*)(w + OFF_WDS);

        prefix_kernel<<<1, 64, 0, stream>>>(cnt, prefix, 1);
        convert_x<<<T / 8, 256, 0, stream>>>(x, Xb);
        gather_x<<<dim3(CAP / 8, E), 256, 0, stream>>>(x, cnt, prefix, tokid, tokw, Xg);
        transpose_cvt<<<dim3(F / 32, H / 32, E), 256, 0, stream>>>(Wg, WgT, H, F);
        transpose_cvt<<<dim3(F / 32, H / 32, E), 256, 0, stream>>>(Wu, WuT, H, F);
        transpose_cvt<<<dim3(H / 32, F / 32, E), 256, 0, stream>>>(Wd, WdT, F, H);
        transpose_cvt<<<dim3(FS / 32, H / 32, 1), 256, 0, stream>>>(Wg_s, WgsT, H, FS);
        transpose_cvt<<<dim3(FS / 32, H / 32, 1), 256, 0, stream>>>(Wu_s, WusT, H, FS);
        transpose_cvt<<<dim3(H / 32, FS / 32, 1), 256, 0, stream>>>(Wd_s, WdsT, FS, H);

        s1_gemm<false><<<dim3(FS / 128, T / 128, 1), 256, 0, stream>>>(
            Xb, WgsT, WusT, Hs, nullptr, nullptr, FS);
        s1_gemm<true><<<dim3(F / 128, CAP / 128, E), 256, 0, stream>>>(
            Xg, WgT, WuT, Hb, cnt, prefix, F);
        s2_gemm<false><<<dim3(H / 128, T / 128, 1), 256, 0, stream>>>(
            Hs, WdsT, out, nullptr, nullptr, nullptr, nullptr, FS);
        s2_gemm<true><<<dim3(H / 128, CAP / 128, E), 256, 0, stream>>>(
            Hb, WdT, out, cnt, prefix, tokid, tokw, F);
    } else {
        // fallback: original fp32-staging path (needs ~40.2 MB)
        bf16* Hs = (bf16*)(w + 262400);
        bf16* Hb = (bf16*)(w + 262400 + (size_t)T * FS * 2);

        prefix_kernel<<<1, 64, 0, stream>>>(cnt, prefix, 0);
        stage1_gemm<false><<<dim3(FS / 128, T / 128, 1), 256, 0, stream>>>(
            x, Wg_s, Wu_s, Hs, nullptr, nullptr, nullptr, nullptr, FS);
        stage1_gemm<true><<<dim3(F / 128, T / 128, E), 256, 0, stream>>>(
            x, Wg, Wu, Hb, cnt, prefix, tokid, tokw, F);
        stage2_gemm<false><<<dim3(H / 128, T / 128, 1), 256, 0, stream>>>(
            Hs, Wd_s, out, nullptr, nullptr, nullptr, nullptr, FS);
        stage2_gemm<true><<<dim3(H / 128, T / 128, E), 256, 0, stream>>>(
            Hb, Wd, out, cnt, prefix, tokid, tokw, F);
    }
}

// Round 2
// 1174.550 us; speedup vs baseline: 1.0732x; 1.0732x over previous
//
#include <hip/hip_runtime.h>

#define H 2048
#define E 16
#define F 1408
#define FS 4096
#define T 2048
#define TOPK 4
#define CAP 2048
#define NPADROWS (T * TOPK + E * 128)  // 10240 padded expert slots
#define NMB (NPADROWS / 128)           // 80 expert m-blocks max
#define NS ((FS / 128) * (T / 128))    // 512 shared s1 blocks
#define GS1 (NS + (F / 128) * NMB)     // 512 + 880 = 1392
#define GS2E ((H / 128) * NMB)         // 1280

typedef __bf16 bf16;
typedef bf16 bf16x4 __attribute__((ext_vector_type(4)));
typedef bf16 bf16x8 __attribute__((ext_vector_type(8)));
typedef float floatx4 __attribute__((ext_vector_type(4)));

static __device__ __forceinline__ floatx4 mfma16(bf16x8 a, bf16x8 b, floatx4 c) {
    return __builtin_amdgcn_mfma_f32_16x16x32_bf16(a, b, c, 0, 0, 0);
}

// async global->LDS, 16B per lane; LDS dest must be wave-uniform (HW adds lane*16)
static __device__ __forceinline__ void gload16(const bf16* g, bf16* l) {
    __builtin_amdgcn_global_load_lds(
        (const __attribute__((address_space(1))) void*)g,
        (__attribute__((address_space(3))) void*)l, 16, 0, 0);
}

// ---------------- router ----------------
__global__ __launch_bounds__(256) void router_kernel(
    const float* __restrict__ x, const float* __restrict__ wr,
    int* __restrict__ cnt, int* __restrict__ tokid, float* __restrict__ tokw) {
    const int wave = threadIdx.x >> 6;
    const int lane = threadIdx.x & 63;
    const int t = blockIdx.x * 4 + wave;
    if (t >= T) return;
    const float* xrow = x + (size_t)t * H;
    float xr[H / 64];
#pragma unroll
    for (int i = 0; i < H / 64; i++) xr[i] = xrow[lane + i * 64];
    float logits[E];
    for (int e = 0; e < E; e++) {
        const float* wrow = wr + (size_t)e * H;
        float p = 0.f;
#pragma unroll
        for (int i = 0; i < H / 64; i++) p += xr[i] * wrow[lane + i * 64];
        for (int off = 32; off; off >>= 1) p += __shfl_xor(p, off, 64);
        logits[e] = p;
    }
    float mx = logits[0];
    for (int e = 1; e < E; e++) mx = fmaxf(mx, logits[e]);
    float pr[E];
    float sum = 0.f;
    for (int e = 0; e < E; e++) { pr[e] = __expf(logits[e] - mx); sum += pr[e]; }
    float inv = 1.f / sum;
    for (int e = 0; e < E; e++) pr[e] *= inv;
    int sel[TOPK]; float sw[TOPK]; float wsum = 0.f;
    for (int k = 0; k < TOPK; k++) {
        float best = -1.f; int bi = 0;
        for (int e = 0; e < E; e++) if (pr[e] > best) { best = pr[e]; bi = e; }
        sel[k] = bi; sw[k] = best; wsum += best; pr[bi] = -2.f;
    }
    if (lane == 0) {
        float invw = 1.f / wsum;
        for (int k = 0; k < TOPK; k++) {
            int e = sel[k];
            int pos = atomicAdd(&cnt[e], 1);
            tokid[e * CAP + pos] = t;
            tokw[e * CAP + pos] = sw[k] * invw;
        }
    }
}

// prefix with per-expert padding to 128 rows
__global__ void prefix_kernel(const int* __restrict__ cnt, int* __restrict__ prefix) {
    if (threadIdx.x == 0) {
        int s = 0;
        for (int e = 0; e < E; e++) { prefix[e] = s; s += (cnt[e] + 127) & ~127; }
        prefix[E] = s;
    }
}

// ---------------- pre-pass: x -> bf16, (row&7) k-group swizzle ----------------
__global__ __launch_bounds__(256) void convert_x(const float* __restrict__ x,
                                                 bf16* __restrict__ Xb) {
    const int t = threadIdx.x;
    const int row = blockIdx.x * 8 + (t >> 5);
    const int l32 = t & 31;
    const float* src = x + (size_t)row * H;
    bf16* dst = Xb + (size_t)row * H;
    const int xk = (row & 7) << 3;
#pragma unroll
    for (int i = 0; i < 8; i++) {
        int kb = l32 * 8 + i * 256;
        float4 a = *(const float4*)(src + kb);
        float4 b = *(const float4*)(src + kb + 4);
        bf16x8 v;
        v[0] = (bf16)a.x; v[1] = (bf16)a.y; v[2] = (bf16)a.z; v[3] = (bf16)a.w;
        v[4] = (bf16)b.x; v[5] = (bf16)b.y; v[6] = (bf16)b.z; v[7] = (bf16)b.w;
        *(bf16x8*)(dst + (kb ^ xk)) = v;
    }
}

// ---------------- pre-pass: gathered+scaled expert tokens ----------------
__global__ __launch_bounds__(256) void gather_x(
    const float* __restrict__ x, const int* __restrict__ cnt,
    const int* __restrict__ prefixPad, const int* __restrict__ tokid,
    const float* __restrict__ tokw, bf16* __restrict__ Xg) {
    const int e = blockIdx.y;
    const int s0 = blockIdx.x * 8;
    const int n = cnt[e];
    if (s0 >= n) return;
    const int t = threadIdx.x;
    const int sl = s0 + (t >> 5);
    const int l32 = t & 31;
    if (sl >= n) return;
    const int tok = tokid[e * CAP + sl];
    const float w = tokw[e * CAP + sl];
    const int row = prefixPad[e] + sl;
    const float* src = x + (size_t)tok * H;
    bf16* dst = Xg + (size_t)row * H;
    const int xk = (row & 7) << 3;
#pragma unroll
    for (int i = 0; i < 8; i++) {
        int kb = l32 * 8 + i * 256;
        float4 a = *(const float4*)(src + kb);
        float4 b = *(const float4*)(src + kb + 4);
        bf16x8 v;
        v[0] = (bf16)(a.x * w); v[1] = (bf16)(a.y * w);
        v[2] = (bf16)(a.z * w); v[3] = (bf16)(a.w * w);
        v[4] = (bf16)(b.x * w); v[5] = (bf16)(b.y * w);
        v[6] = (bf16)(b.z * w); v[7] = (bf16)(b.w * w);
        *(bf16x8*)(dst + (kb ^ xk)) = v;
    }
}

// ---------------- pre-pass: transpose fp32 [z][R][C] -> bf16 [z][C][R], swizzled ----------------
// 64(r) x 32(c) tiles; fp32 LDS [64][33] => conflict-free column reads; 16B stores.
__global__ __launch_bounds__(256) void transpose_cvt(
    const float* __restrict__ src, bf16* __restrict__ dst, int R, int C) {
    __shared__ float tile[64][33];
    const int t = threadIdx.x;
    const size_t zb = (size_t)blockIdx.z * R * C;
    const int r0 = blockIdx.y * 64, c0 = blockIdx.x * 32;
    {
        const int rl = t >> 2, c8 = (t & 3) * 8;
        const float* s = src + zb + (size_t)(r0 + rl) * C + c0 + c8;
        float4 v0 = *(const float4*)s;
        float4 v1 = *(const float4*)(s + 4);
        tile[rl][c8 + 0] = v0.x; tile[rl][c8 + 1] = v0.y;
        tile[rl][c8 + 2] = v0.z; tile[rl][c8 + 3] = v0.w;
        tile[rl][c8 + 4] = v1.x; tile[rl][c8 + 5] = v1.y;
        tile[rl][c8 + 6] = v1.z; tile[rl][c8 + 7] = v1.w;
    }
    __syncthreads();
    {
        const int cl = t >> 3, r8 = (t & 7) * 8;
        bf16x8 o;
#pragma unroll
        for (int i = 0; i < 8; i++) o[i] = (bf16)tile[r8 + i][cl];
        const int cg = c0 + cl;
        *(bf16x8*)(dst + zb + (size_t)cg * R + ((r0 + r8) ^ ((cg & 7) << 3))) = o;
    }
}

// ---------------- merged stage 1: shared + expert FFN1 in one dispatch ----------------
// All operands bf16, [*][K] row-major with (row&7) k-group swizzle. BK=64.
__global__ __launch_bounds__(256, 2) void s1_all(
    const bf16* __restrict__ Xb, const bf16* __restrict__ Xg,
    const bf16* __restrict__ WgsT, const bf16* __restrict__ WusT,
    const bf16* __restrict__ WgT, const bf16* __restrict__ WuT,
    bf16* __restrict__ Hs, bf16* __restrict__ Hb,
    const int* __restrict__ cnt, const int* __restrict__ prefixPad) {
    __shared__ __align__(16) bf16 As[128 * 64];
    __shared__ __align__(16) bf16 Bgs[128 * 64];
    __shared__ __align__(16) bf16 Bus[128 * 64];

    const int raw = blockIdx.x;
    const int id = (raw & 7) * (GS1 / 8) + (raw >> 3);  // XCD-chunked

    int n0, m0, ne, nF;
    const bf16 *A, *bg, *bu;
    bf16* hb;
    if (id < NS) {
        // shared FFN1: id = n*16 + m (m fast -> B panel L2-hot per run)
        m0 = (id & 15) * 128;
        n0 = (id >> 4) * 128;
        ne = 1 << 30;
        nF = FS;
        A = Xb; bg = WgsT; bu = WusT; hb = Hs;
    } else {
        const int id2 = id - NS;
        const int mb = id2 % NMB;   // m fast
        const int xx = id2 / NMB;
        const int rowbase = mb * 128;
        if (rowbase >= prefixPad[E]) return;
        int e = 0;
        while (prefixPad[e + 1] <= rowbase) e++;
        const int pp = prefixPad[e];
        m0 = rowbase - pp;
        ne = cnt[e];
        n0 = xx * 128;
        nF = F;
        A = Xg + (size_t)pp * H;
        bg = WgT + (size_t)e * F * H;
        bu = WuT + (size_t)e * F * H;
        hb = Hb + (size_t)pp * F;
    }

    const int tid = threadIdx.x;
    const int lane = tid & 63;
    const int wave = tid >> 6;
    // staging: wave w stages 32 rows; round j covers rows [w*32+j*8, +8)
    const bf16* aP = A + (size_t)(m0 + wave * 32 + (lane >> 3)) * H + (lane & 7) * 8;
    const bf16* gP = bg + (size_t)(n0 + wave * 32 + (lane >> 3)) * H + (lane & 7) * 8;
    const bf16* uP = bu + (size_t)(n0 + wave * 32 + (lane >> 3)) * H + (lane & 7) * 8;

    const int m_ = lane & 15;
    const int quad = lane >> 4;
    const int wm = (wave & 1) * 64;
    const int wn = (wave >> 1) * 64;

    floatx4 accg[4][4], accu[4][4];
#pragma unroll
    for (int i = 0; i < 4; i++)
#pragma unroll
        for (int j = 0; j < 4; j++) {
            accg[i][j] = (floatx4){0.f, 0.f, 0.f, 0.f};
            accu[i][j] = (floatx4){0.f, 0.f, 0.f, 0.f};
        }

    for (int k0 = 0; k0 < H; k0 += 64) {
#pragma unroll
        for (int j = 0; j < 4; j++) {
            gload16(aP + k0 + (size_t)j * 8 * H, &As[wave * 2048 + j * 512]);
            gload16(gP + k0 + (size_t)j * 8 * H, &Bgs[wave * 2048 + j * 512]);
            gload16(uP + k0 + (size_t)j * 8 * H, &Bus[wave * 2048 + j * 512]);
        }
        __syncthreads();
#pragma unroll
        for (int kk = 0; kk < 2; kk++) {
            const int ko = (((kk << 2) | quad) ^ (m_ & 7)) << 3;
            bf16x8 af[4], bgf[4], buf_[4];
#pragma unroll
            for (int mi = 0; mi < 4; mi++)
                af[mi] = *(const bf16x8*)&As[(wm + mi * 16 + m_) * 64 + ko];
#pragma unroll
            for (int ni = 0; ni < 4; ni++) {
                bgf[ni] = *(const bf16x8*)&Bgs[(wn + ni * 16 + m_) * 64 + ko];
                buf_[ni] = *(const bf16x8*)&Bus[(wn + ni * 16 + m_) * 64 + ko];
            }
#pragma unroll
            for (int mi = 0; mi < 4; mi++)
#pragma unroll
                for (int ni = 0; ni < 4; ni++) {
                    accg[mi][ni] = mfma16(af[mi], bgf[ni], accg[mi][ni]);
                    accu[mi][ni] = mfma16(af[mi], buf_[ni], accu[mi][ni]);
                }
        }
        __syncthreads();
    }

    // epilogue: silu(g)*u -> bf16, swizzled for s2's staging
#pragma unroll
    for (int mi = 0; mi < 4; mi++)
#pragma unroll
        for (int ni = 0; ni < 4; ni++)
#pragma unroll
            for (int r = 0; r < 4; r++) {
                int row = m0 + wm + mi * 16 + quad * 4 + r;
                int col = n0 + wn + ni * 16 + m_;
                if (row < ne) {
                    float g = accg[mi][ni][r];
                    float u = accu[mi][ni][r];
                    float hv = g / (1.f + __expf(-g)) * u;
                    hb[(size_t)row * nF + (col ^ ((row & 7) << 3))] = (bf16)hv;
                }
            }
}

// ---------------- stage 2: out (+)= h @ WdT ----------------
template <bool EXPERT>
__global__ __launch_bounds__(256, 2) void s2_gemm(
    const bf16* __restrict__ hin, const bf16* __restrict__ BdT,
    float* __restrict__ out, const int* __restrict__ cnt,
    const int* __restrict__ prefixPad, const int* __restrict__ tokid,
    const float* __restrict__ tokw, int nK) {
    __shared__ __align__(16) bf16 As[128 * 64];
    __shared__ __align__(16) bf16 Bs[128 * 64];
    const int raw = blockIdx.x;
    const int id = EXPERT ? (raw & 7) * (GS2E / 8) + (raw >> 3)
                          : (raw & 7) * 32 + (raw >> 3);
    int n0, m0, ne, e = 0;
    const bf16 *A, *B;
    if (EXPERT) {
        const int mb = id % NMB;
        const int xx = id / NMB;
        const int rowbase = mb * 128;
        if (rowbase >= prefixPad[E]) return;
        while (prefixPad[e + 1] <= rowbase) e++;
        const int pp = prefixPad[e];
        m0 = rowbase - pp;
        ne = cnt[e];
        n0 = xx * 128;
        A = hin + (size_t)pp * F;
        B = BdT + (size_t)e * F * H;
    } else {
        m0 = (id & 15) * 128;
        n0 = (id >> 4) * 128;
        ne = 1 << 30;
        A = hin; B = BdT;
    }
    const int tid = threadIdx.x;
    const int lane = tid & 63;
    const int wave = tid >> 6;
    const bf16* aP = A + (size_t)(m0 + wave * 32 + (lane >> 3)) * nK + (lane & 7) * 8;
    const bf16* bP = B + (size_t)(n0 + wave * 32 + (lane >> 3)) * nK + (lane & 7) * 8;

    const int m_ = lane & 15;
    const int quad = lane >> 4;
    const int wm = (wave & 1) * 64;
    const int wn = (wave >> 1) * 64;

    floatx4 acc[4][4];
#pragma unroll
    for (int i = 0; i < 4; i++)
#pragma unroll
        for (int j = 0; j < 4; j++) acc[i][j] = (floatx4){0.f, 0.f, 0.f, 0.f};

    for (int k0 = 0; k0 < nK; k0 += 64) {
#pragma unroll
        for (int j = 0; j < 4; j++) {
            gload16(aP + k0 + (size_t)j * 8 * nK, &As[wave * 2048 + j * 512]);
            gload16(bP + k0 + (size_t)j * 8 * nK, &Bs[wave * 2048 + j * 512]);
        }
        __syncthreads();
#pragma unroll
        for (int kk = 0; kk < 2; kk++) {
            const int ko = (((kk << 2) | quad) ^ (m_ & 7)) << 3;
            bf16x8 af[4], bf_[4];
#pragma unroll
            for (int mi = 0; mi < 4; mi++)
                af[mi] = *(const bf16x8*)&As[(wm + mi * 16 + m_) * 64 + ko];
#pragma unroll
            for (int ni = 0; ni < 4; ni++)
                bf_[ni] = *(const bf16x8*)&Bs[(wn + ni * 16 + m_) * 64 + ko];
#pragma unroll
            for (int mi = 0; mi < 4; mi++)
#pragma unroll
                for (int ni = 0; ni < 4; ni++)
                    acc[mi][ni] = mfma16(af[mi], bf_[ni], acc[mi][ni]);
        }
        __syncthreads();
    }

#pragma unroll
    for (int mi = 0; mi < 4; mi++)
#pragma unroll
        for (int ni = 0; ni < 4; ni++)
#pragma unroll
            for (int r = 0; r < 4; r++) {
                int row = m0 + wm + mi * 16 + quad * 4 + r;
                int col = n0 + wn + ni * 16 + m_;
                if (EXPERT) {
                    if (row < ne) {
                        int t = tokid[e * CAP + row];
                        float wgt = tokw[e * CAP + row];
                        atomicAdd(out + (size_t)t * H + col, acc[mi][ni][r] * wgt);
                    }
                } else {
                    out[(size_t)row * H + col] = acc[mi][ni][r];
                }
            }
}

extern "C" void kernel_launch(void* const* d_in, const int* in_sizes, int n_in,
                              void* d_out, int out_size, void* d_ws, size_t ws_size,
                              hipStream_t stream) {
    const float* x = (const float*)d_in[0];
    const float* w_router = (const float*)d_in[1];
    const float* Wg = (const float*)d_in[2];
    const float* Wu = (const float*)d_in[3];
    const float* Wd = (const float*)d_in[4];
    const float* Wg_s = (const float*)d_in[5];
    const float* Wu_s = (const float*)d_in[6];
    const float* Wd_s = (const float*)d_in[7];
    float* out = (float*)d_out;

    char* w = (char*)d_ws;
    int* cnt = (int*)(w + 0);
    int* prefix = (int*)(w + 64);
    int* tokid = (int*)(w + 256);
    float* tokw = (float*)(w + 256 + (size_t)E * CAP * 4);

    constexpr size_t OFF_XB = 262400;
    constexpr size_t OFF_XG = OFF_XB + (size_t)T * H * 2;
    constexpr size_t OFF_HS = OFF_XG + (size_t)NPADROWS * H * 2;
    constexpr size_t OFF_HB = OFF_HS + (size_t)T * FS * 2;
    constexpr size_t OFF_WGT = OFF_HB + (size_t)NPADROWS * F * 2;
    constexpr size_t OFF_WUT = OFF_WGT + (size_t)E * F * H * 2;
    constexpr size_t OFF_WDT = OFF_WUT + (size_t)E * F * H * 2;
    constexpr size_t OFF_WGS = OFF_WDT + (size_t)E * F * H * 2;
    constexpr size_t OFF_WUS = OFF_WGS + (size_t)H * FS * 2;
    constexpr size_t OFF_WDS = OFF_WUS + (size_t)H * FS * 2;

    bf16* Xb = (bf16*)(w + OFF_XB);
    bf16* Xg = (bf16*)(w + OFF_XG);
    bf16* Hs = (bf16*)(w + OFF_HS);
    bf16* Hb = (bf16*)(w + OFF_HB);
    bf16* WgT = (bf16*)(w + OFF_WGT);
    bf16* WuT = (bf16*)(w + OFF_WUT);
    bf16* WdT = (bf16*)(w + OFF_WDT);
    bf16* WgsT = (bf16*)(w + OFF_WGS);
    bf16* WusT = (bf16*)(w + OFF_WUS);
    bf16* WdsT = (bf16*)(w + OFF_WDS);

    hipMemsetAsync(cnt, 0, 64, stream);
    router_kernel<<<T / 4, 256, 0, stream>>>(x, w_router, cnt, tokid, tokw);
    prefix_kernel<<<1, 64, 0, stream>>>(cnt, prefix);

    convert_x<<<T / 8, 256, 0, stream>>>(x, Xb);
    gather_x<<<dim3(CAP / 8, E), 256, 0, stream>>>(x, cnt, prefix, tokid, tokw, Xg);
    transpose_cvt<<<dim3(F / 32, H / 64, E), 256, 0, stream>>>(Wg, WgT, H, F);
    transpose_cvt<<<dim3(F / 32, H / 64, E), 256, 0, stream>>>(Wu, WuT, H, F);
    transpose_cvt<<<dim3(H / 32, F / 64, E), 256, 0, stream>>>(Wd, WdT, F, H);
    transpose_cvt<<<dim3(FS / 32, H / 64, 1), 256, 0, stream>>>(Wg_s, WgsT, H, FS);
    transpose_cvt<<<dim3(FS / 32, H / 64, 1), 256, 0, stream>>>(Wu_s, WusT, H, FS);
    transpose_cvt<<<dim3(H / 32, FS / 64, 1), 256, 0, stream>>>(Wd_s, WdsT, FS, H);

    s1_all<<<GS1, 256, 0, stream>>>(Xb, Xg, WgsT, WusT, WgT, WuT, Hs, Hb, cnt, prefix);

    // shared stage2 writes every out element exactly once; expert stage2
    // atomically accumulates on top (stream-ordered after it).
    s2_gemm<false><<<(H / 128) * (T / 128), 256, 0, stream>>>(
        Hs, WdsT, out, nullptr, nullptr, nullptr, nullptr, FS);
    s2_gemm<true><<<GS2E, 256, 0, stream>>>(
        Hb, WdT, out, cnt, prefix, tokid, tokw, F);
}